// Round 2
// baseline (1064.269 us; speedup 1.0000x reference)
//
#include <hip/hip_runtime.h>

// VectorQuantizationLayer1D: N=262144 pts, D=64, K=1024 codewords.
// out (float32): [0,N) idx-as-float | [N,2N) dist | [2N,..) gathered codewords.
//
// Round 2: one point per thread, x held in 64 VGPRs; codeword stream is
// wave-uniform -> scalar loads (s_load_dwordx16) + SGPR-broadcast FMA.
// Zero LDS traffic in the inner loop (round 1 was 3x LDS-BW-bound).

#define N_PTS 262144
#define K_CW  1024
#define DIM   64

__device__ __forceinline__ float dot4(float4 a, float4 b) {
    return a.x*b.x + a.y*b.y + a.z*b.z + a.w*b.w;
}

__launch_bounds__(256, 4)
__global__ void vq_kernel(const float* __restrict__ x,
                          const float* __restrict__ cw,
                          float* __restrict__ out) {
    __shared__ float sc2[K_CW];   // ||c||^2, read as uniform broadcast
    __shared__ int   sbest[256];

    const int tid = threadIdx.x;
    const int point = blockIdx.x * 256 + tid;
    const float4* __restrict__ cv = (const float4*)cw;

    // ---- per-block ||c||^2 precompute (4 codewords/thread) ----
    #pragma unroll
    for (int r = 0; r < 4; ++r) {
        const int k = r * 256 + tid;
        const float4* cp = cv + k * 16;
        float s0 = 0.f, s1 = 0.f, s2 = 0.f, s3 = 0.f;
        #pragma unroll
        for (int j = 0; j < 16; j += 4) {
            float4 a = cp[j], b = cp[j + 1], c = cp[j + 2], d = cp[j + 3];
            s0 += dot4(a, a); s1 += dot4(b, b);
            s2 += dot4(c, c); s3 += dot4(d, d);
        }
        sc2[k] = (s0 + s1) + (s2 + s3);
    }

    // ---- this thread's point -> 16 float4 in VGPRs ----
    float4 xv[16];
    const float4* xg = (const float4*)x + (size_t)point * 16;
    #pragma unroll
    for (int j = 0; j < 16; ++j) xv[j] = xg[j];

    float x2;
    {
        float s0 = 0.f, s1 = 0.f, s2 = 0.f, s3 = 0.f;
        #pragma unroll
        for (int j = 0; j < 16; j += 4) {
            s0 += dot4(xv[j + 0], xv[j + 0]);
            s1 += dot4(xv[j + 1], xv[j + 1]);
            s2 += dot4(xv[j + 2], xv[j + 2]);
            s3 += dot4(xv[j + 3], xv[j + 3]);
        }
        x2 = (s0 + s1) + (s2 + s3);
    }
    __syncthreads();

    // ---- main loop: 1024 codewords, wave-uniform loads ----
    float best = 3.4e38f;
    int   besti = 0;
    for (int k = 0; k < K_CW; ++k) {
        const float4* cp = cv + k * 16;   // uniform address -> s_load expected
        float d0 = 0.f, d1 = 0.f, d2 = 0.f, d3 = 0.f;
        #pragma unroll
        for (int j = 0; j < 16; j += 4) {
            d0 += dot4(xv[j + 0], cp[j + 0]);
            d1 += dot4(xv[j + 1], cp[j + 1]);
            d2 += dot4(xv[j + 2], cp[j + 2]);
            d3 += dot4(xv[j + 3], cp[j + 3]);
        }
        const float dotv  = (d0 + d1) + (d2 + d3);
        const float score = sc2[k] - 2.f * dotv;   // + x2 is monotonic, add later
        if (score < best) { best = score; besti = k; }  // strict < keeps lowest idx
    }

    // ---- scalar outputs ----
    out[point]         = (float)besti;
    out[N_PTS + point] = sqrtf(fmaxf(x2 + best, 0.f));
    sbest[tid] = besti;
    __syncthreads();

    // ---- coalesced gather of quantized_data: 256 pts x 16 float4 per block ----
    float4* od = (float4*)(out + 2 * (size_t)N_PTS) + (size_t)blockIdx.x * 4096;
    #pragma unroll 4
    for (int w = 0; w < 16; ++w) {
        const int f = w * 256 + tid;
        od[f] = cv[sbest[f >> 4] * 16 + (f & 15)];
    }
}

extern "C" void kernel_launch(void* const* d_in, const int* in_sizes, int n_in,
                              void* d_out, int out_size, void* d_ws, size_t ws_size,
                              hipStream_t stream) {
    const float* x  = (const float*)d_in[0];
    const float* cw = (const float*)d_in[1];
    float* out = (float*)d_out;
    vq_kernel<<<N_PTS / 256, 256, 0, stream>>>(x, cw, out);
}

// Round 3
// 515.148 us; speedup vs baseline: 2.0660x; 2.0660x over previous
//
#include <hip/hip_runtime.h>

// VectorQuantizationLayer1D: N=262144 pts, D=64, K=1024 codewords.
// out (f32): [0,N) idx-as-float | [N,2N) dist | [2N,..) gathered codewords.
//
// Round 3: split-bf16 MFMA (hh+hl+lh passes, score err ~1e-4) for candidate
// selection; per-(lane,slot) top-1 state in VGPRs; LDS merge -> per-point
// top-2; exact fp32 rescore of both candidates decides index + distance.
// Block: 256 thr (4 waves), 128 points, 1 block/CU (114 KB LDS).

#define N_PTS 262144
#define K_CW  1024
#define DIM   64

typedef __attribute__((ext_vector_type(8)))  short short8;
typedef __attribute__((ext_vector_type(16))) float floatx16;

__device__ __forceinline__ unsigned short f2bf(float f) {
    unsigned u = __float_as_uint(f);
    return (unsigned short)((u + 0x7FFFu + ((u >> 16) & 1u)) >> 16);
}
__device__ __forceinline__ float bf2f(unsigned short h) {
    return __uint_as_float(((unsigned)h) << 16);
}
__device__ __forceinline__ float dot4(float4 a, float4 b) {
    return a.x*b.x + a.y*b.y + a.z*b.z + a.w*b.w;
}

__launch_bounds__(256, 1)
__global__ void vq_mfma_kernel(const float* __restrict__ x,
                               const float* __restrict__ cw,
                               float* __restrict__ out) {
    __shared__ float sx[128 * 68];                               // fp32 x tile (stride 68 floats)
    __shared__ __align__(16) unsigned short sB[2 * 256 * 72];    // bf16 hi|lo codeword chunk (stride 72); reused as dump
    __shared__ float sc2[256];
    __shared__ float sx2[128];
    __shared__ int   sidx[128];
    __shared__ float4 sscr[64 * 4];
    __shared__ float sdd[256];
    __shared__ int   sci[256];

    const int tid  = threadIdx.x;
    const int w    = tid >> 6;     // wave 0..3
    const int lane = tid & 63;
    const int q    = lane >> 5;    // half-wave
    const int l31  = lane & 31;
    const int base = blockIdx.x * 128;

    // ---- stage x tile (fp32, coalesced) + fused ||x||^2 ----
    {
        const float4* xg = (const float4*)x + (size_t)base * 16;
        float4* sxf4 = (float4*)sx;
        #pragma unroll
        for (int i = 0; i < 8; ++i) {
            int g = i * 256 + tid;
            int row = g >> 4, c4 = g & 15;
            float4 v = xg[g];
            sxf4[row * 17 + c4] = v;
            float part = dot4(v, v);
            part += __shfl_xor(part, 1);
            part += __shfl_xor(part, 2);
            part += __shfl_xor(part, 4);
            part += __shfl_xor(part, 8);
            if (c4 == 0) sx2[row] = part;
        }
    }
    __syncthreads();

    // ---- build A fragments in VGPRs: 4 row-tiles x 4 K-steps, hi+lo bf16 ----
    // A[m=lane&31][k = q*8 + j] per 32x32x16 mfma; K-step advances k by 16.
    short8 ah[4][4], al[4][4];
    {
        const float4* sxf4 = (const float4*)sx;
        #pragma unroll
        for (int rt = 0; rt < 4; ++rt) {
            const int m = rt * 32 + l31;
            #pragma unroll
            for (int ks = 0; ks < 4; ++ks) {
                float4 va = sxf4[m * 17 + ks * 4 + q * 2];
                float4 vb = sxf4[m * 17 + ks * 4 + q * 2 + 1];
                float f[8] = {va.x, va.y, va.z, va.w, vb.x, vb.y, vb.z, vb.w};
                short8 h, l;
                #pragma unroll
                for (int j = 0; j < 8; ++j) {
                    unsigned short hb = f2bf(f[j]);
                    h[j] = (short)hb;
                    l[j] = (short)f2bf(f[j] - bf2f(hb));
                }
                ah[rt][ks] = h; al[rt][ks] = l;
            }
        }
    }

    // per-(lane,slot) running best: slot = rt*16 + reg  (64 fixed points/lane)
    float bs[64];
    int   bi[64];
    #pragma unroll
    for (int s = 0; s < 64; ++s) { bs[s] = 3.4e38f; bi[s] = 0; }

    // ---- 4 chunks of 256 codewords ----
    for (int ch = 0; ch < 4; ++ch) {
        // stage B chunk: coalesced fp32 read -> bf16 hi/lo split + fused ||c||^2
        {
            const float4* cg = (const float4*)cw + ch * 4096;
            #pragma unroll
            for (int i = 0; i < 16; ++i) {
                int g = i * 256 + tid;
                int row = g >> 4, c4 = g & 15;
                float4 v = cg[g];
                unsigned short h0 = f2bf(v.x), h1 = f2bf(v.y), h2 = f2bf(v.z), h3 = f2bf(v.w);
                unsigned short l0 = f2bf(v.x - bf2f(h0)), l1 = f2bf(v.y - bf2f(h1)),
                               l2 = f2bf(v.z - bf2f(h2)), l3 = f2bf(v.w - bf2f(h3));
                uint2 hv, lv;
                hv.x = (unsigned)h0 | ((unsigned)h1 << 16);
                hv.y = (unsigned)h2 | ((unsigned)h3 << 16);
                lv.x = (unsigned)l0 | ((unsigned)l1 << 16);
                lv.y = (unsigned)l2 | ((unsigned)l3 << 16);
                *(uint2*)&sB[row * 72 + c4 * 4]         = hv;
                *(uint2*)&sB[18432 + row * 72 + c4 * 4] = lv;
                float part = dot4(v, v);
                part += __shfl_xor(part, 1);
                part += __shfl_xor(part, 2);
                part += __shfl_xor(part, 4);
                part += __shfl_xor(part, 8);
                if (c4 == 0) sc2[row] = part;
            }
        }
        __syncthreads();

        // each wave: 2 cw-tiles of 32 (tiles w and w+4 of this chunk)
        #pragma unroll
        for (int t2 = 0; t2 < 2; ++t2) {
            const int tt = w + t2 * 4;              // chunk-local cw-tile
            const int nn = tt * 32 + l31;           // B row (codeword) for this lane
            short8 bh[4], bl[4];
            #pragma unroll
            for (int ks = 0; ks < 4; ++ks) {
                bh[ks] = *(const short8*)&sB[nn * 72 + ks * 16 + q * 8];
                bl[ks] = *(const short8*)&sB[18432 + nn * 72 + ks * 16 + q * 8];
            }
            floatx16 acc[4];
            #pragma unroll
            for (int rt = 0; rt < 4; ++rt)
                #pragma unroll
                for (int r = 0; r < 16; ++r) acc[rt][r] = 0.f;

            #pragma unroll
            for (int ks = 0; ks < 4; ++ks) {
                #pragma unroll
                for (int rt = 0; rt < 4; ++rt)
                    acc[rt] = __builtin_amdgcn_mfma_f32_32x32x16_bf16(ah[rt][ks], bh[ks], acc[rt], 0, 0, 0);
                #pragma unroll
                for (int rt = 0; rt < 4; ++rt)
                    acc[rt] = __builtin_amdgcn_mfma_f32_32x32x16_bf16(al[rt][ks], bh[ks], acc[rt], 0, 0, 0);
                #pragma unroll
                for (int rt = 0; rt < 4; ++rt)
                    acc[rt] = __builtin_amdgcn_mfma_f32_32x32x16_bf16(ah[rt][ks], bl[ks], acc[rt], 0, 0, 0);
            }

            const float c2v  = sc2[tt * 32 + l31];
            const int   idxv = ch * 256 + tt * 32 + l31;
            #pragma unroll
            for (int rt = 0; rt < 4; ++rt)
                #pragma unroll
                for (int r = 0; r < 16; ++r) {
                    float s = fmaf(-2.f, acc[rt][r], c2v);  // ||c||^2 - 2 x.c
                    const int slot = rt * 16 + r;
                    bool lt = s < bs[slot];
                    bs[slot] = lt ? s : bs[slot];
                    bi[slot] = lt ? idxv : bi[slot];
                }
        }
        __syncthreads();
    }

    // ---- merge per-lane top-1s -> per-point top-2 candidates (2 rounds of 64 pts) ----
    float2* dump = (float2*)sB;   // 64 pts x 128 entries x 8 B = 64 KB (reuses B chunk LDS)
    for (int rnd = 0; rnd < 2; ++rnd) {
        #pragma unroll
        for (int rt2 = 0; rt2 < 2; ++rt2) {
            const int rt = rnd * 2 + rt2;
            #pragma unroll
            for (int r = 0; r < 16; ++r) {
                const int slot = rt * 16 + r;
                const int p  = rt * 32 + (r & 3) + 8 * (r >> 2) + 4 * q;  // C-layout row
                const int pl = p - rnd * 64;
                float2 e; e.x = bs[slot]; e.y = __int_as_float(bi[slot]);
                dump[pl * 128 + w * 32 + l31] = e;
            }
        }
        __syncthreads();
        {   // stage 1: thread = (point, quarter), scan 32 entries (swizzled vs banks)
            const int pl = tid >> 2, qu = tid & 3;
            float b0 = 3.4e38f, b1 = 3.4e38f; int i0 = 0, i1 = 0;
            for (int e = 0; e < 32; ++e) {
                float2 v = dump[pl * 128 + qu * 32 + ((e + tid) & 31)];
                int ii = __float_as_int(v.y);
                if (v.x < b0)      { b1 = b0; i1 = i0; b0 = v.x; i0 = ii; }
                else if (v.x < b1) { b1 = v.x; i1 = ii; }
            }
            sscr[pl * 4 + qu] = make_float4(b0, __int_as_float(i0), b1, __int_as_float(i1));
        }
        __syncthreads();
        if (tid < 64) {   // stage 2: merge 4 sorted pairs -> top-2
            float b0 = 3.4e38f, b1 = 3.4e38f; int i0 = 0, i1 = 0;
            #pragma unroll
            for (int qu = 0; qu < 4; ++qu) {
                float4 v = sscr[tid * 4 + qu];
                int ia = __float_as_int(v.y), ib = __float_as_int(v.w);
                if (v.x < b0)      { b1 = b0; i1 = i0; b0 = v.x; i0 = ia; }
                else if (v.x < b1) { b1 = v.x; i1 = ia; }
                if (v.z < b0)      { b1 = b0; i1 = i0; b0 = v.z; i0 = ib; }
                else if (v.z < b1) { b1 = v.z; i1 = ib; }
            }
            const int p = rnd * 64 + tid;
            sci[p * 2]     = i0;
            sci[p * 2 + 1] = i1;
        }
        __syncthreads();
    }

    // ---- exact fp32 rescore of both candidates (2 threads per point) ----
    {
        const int p  = tid >> 1;
        const int ii = sci[tid];
        const float4* cr4  = (const float4*)(cw + (size_t)ii * 64);
        const float4* sxf4 = (const float4*)sx;
        float dxc = 0.f, dcc = 0.f;
        #pragma unroll
        for (int k4 = 0; k4 < 16; ++k4) {
            float4 cv = cr4[k4];
            float4 xv = sxf4[p * 17 + k4];
            dxc += dot4(xv, cv);
            dcc += dot4(cv, cv);
        }
        sdd[tid] = (sx2[p] + dcc) - 2.f * dxc;
    }
    __syncthreads();
    if (tid < 128) {
        float da = sdd[tid * 2], db = sdd[tid * 2 + 1];
        int   ia = sci[tid * 2], ib = sci[tid * 2 + 1];
        bool ta = (da < db) || (da == db && ia < ib);   // tie -> lower index (np argmin)
        int   bidx = ta ? ia : ib;
        float bd   = ta ? da : db;
        out[base + tid]         = (float)bidx;
        out[N_PTS + base + tid] = sqrtf(fmaxf(bd, 0.f));
        sidx[tid] = bidx;
    }
    __syncthreads();

    // ---- gather quantized_data (coalesced writes) ----
    {
        float4* od = (float4*)(out + 2 * (size_t)N_PTS) + (size_t)base * 16;
        const float4* c4p = (const float4*)cw;
        #pragma unroll
        for (int i = 0; i < 8; ++i) {
            int g = i * 256 + tid;
            od[g] = c4p[(size_t)sidx[g >> 4] * 16 + (g & 15)];
        }
    }
}

extern "C" void kernel_launch(void* const* d_in, const int* in_sizes, int n_in,
                              void* d_out, int out_size, void* d_ws, size_t ws_size,
                              hipStream_t stream) {
    const float* x  = (const float*)d_in[0];
    const float* cw = (const float*)d_in[1];
    float* out = (float*)d_out;
    vq_mfma_kernel<<<N_PTS / 128, 256, 0, stream>>>(x, cw, out);
}

// Round 4
// 281.212 us; speedup vs baseline: 3.7846x; 1.8319x over previous
//
#include <hip/hip_runtime.h>

// VectorQuantizationLayer1D: N=262144 pts, D=64, K=1024 codewords.
// out (f32): [0,N) idx-as-float | [N,2N) dist | [2N,..) gathered codewords.
//
// Round 4: occupancy-first restructure of the round-3 split-bf16 MFMA design.
// Block = 256 thr (4 waves) / 256 points; wave owns 64 pts (2 row-tiles ->
// 24 MFMA per 8 ds_read_b128, LDS pipe ~50%). LDS 44 KB, VGPR-capped at
// 2 waves/SIMD (2 blocks/CU, 2x round 3's residency). Selection = running
// top-1 per (lane,slot) -> shfl top-2 butterfly -> exact fp32 diff^2 rescore.

#define N_PTS 262144
#define K_CW  1024
#define DIM   64

typedef __attribute__((ext_vector_type(8)))  short short8;
typedef __attribute__((ext_vector_type(16))) float floatx16;

__device__ __forceinline__ unsigned short f2bf(float f) {
    unsigned u = __float_as_uint(f);
    return (unsigned short)((u + 0x7FFFu + ((u >> 16) & 1u)) >> 16);
}
__device__ __forceinline__ float bf2f(unsigned short h) {
    return __uint_as_float(((unsigned)h) << 16);
}
__device__ __forceinline__ float dot4(float4 a, float4 b) {
    return a.x*b.x + a.y*b.y + a.z*b.z + a.w*b.w;
}

__launch_bounds__(256, 2)
__global__ void vq_kernel(const float* __restrict__ x,
                          const float* __restrict__ cw,
                          float* __restrict__ out) {
    // B chunk: 128 cw x 64 dims, hi|lo bf16, row stride 72 shorts (144 B:
    // b128 frag reads 16B-aligned, 4-way bank alias ~1.58x on 8/96 cy -> noise).
    __shared__ __align__(16) unsigned short sB[2 * 128 * 72];   // 36.9 KB
    __shared__ float sc2[128];
    __shared__ int   sci[512];
    __shared__ float sdd[512];
    __shared__ int   sidx[256];

    const int tid  = threadIdx.x;
    const int w    = tid >> 6;     // wave 0..3
    const int lane = tid & 63;
    const int q    = lane >> 5;    // half-wave -> k-segment
    const int l31  = lane & 31;    // B column / A row-in-tile
    const int base = blockIdx.x * 256;
    const float4* __restrict__ x4  = (const float4*)x;
    const float4* __restrict__ c4p = (const float4*)cw;

    // ---- A fragments straight from global: wave w owns rows [w*64, w*64+64) ----
    // A[m=l31][k = 16*ks + 8*q + j], hi+lo bf16 split.
    short8 ah[2][4], al[2][4];
    #pragma unroll
    for (int rt = 0; rt < 2; ++rt) {
        const int row = w * 64 + rt * 32 + l31;
        const float4* xr = x4 + (size_t)(base + row) * 16;
        #pragma unroll
        for (int ks = 0; ks < 4; ++ks) {
            float4 va = xr[ks * 4 + q * 2];
            float4 vb = xr[ks * 4 + q * 2 + 1];
            float f[8] = {va.x, va.y, va.z, va.w, vb.x, vb.y, vb.z, vb.w};
            short8 h, l;
            #pragma unroll
            for (int j = 0; j < 8; ++j) {
                unsigned short hb = f2bf(f[j]);
                h[j] = (short)hb;
                l[j] = (short)f2bf(f[j] - bf2f(hb));
            }
            ah[rt][ks] = h; al[rt][ks] = l;
        }
    }

    // running top-1 per (lane, slot); slot = rt*16 + reg covers 32 of wave's 64 pts
    float bs[32]; int bi[32];
    #pragma unroll
    for (int s = 0; s < 32; ++s) { bs[s] = 3.4e38f; bi[s] = 0; }

    // ---- K loop: 8 chunks of 128 codewords ----
    for (int ch = 0; ch < 8; ++ch) {
        __syncthreads();   // previous chunk's reads done before overwrite
        {
            const float4* cg = c4p + ch * 2048;
            #pragma unroll
            for (int i = 0; i < 8; ++i) {
                const int g = i * 256 + tid;
                const int row = g >> 4, c4 = g & 15;
                float4 v = cg[g];
                unsigned short h0 = f2bf(v.x), h1 = f2bf(v.y), h2 = f2bf(v.z), h3 = f2bf(v.w);
                unsigned short l0 = f2bf(v.x - bf2f(h0)), l1 = f2bf(v.y - bf2f(h1)),
                               l2 = f2bf(v.z - bf2f(h2)), l3 = f2bf(v.w - bf2f(h3));
                uint2 hv, lv;
                hv.x = (unsigned)h0 | ((unsigned)h1 << 16);
                hv.y = (unsigned)h2 | ((unsigned)h3 << 16);
                lv.x = (unsigned)l0 | ((unsigned)l1 << 16);
                lv.y = (unsigned)l2 | ((unsigned)l3 << 16);
                *(uint2*)&sB[row * 72 + c4 * 4]        = hv;
                *(uint2*)&sB[9216 + row * 72 + c4 * 4] = lv;
                float part = dot4(v, v);
                part += __shfl_xor(part, 1);
                part += __shfl_xor(part, 2);
                part += __shfl_xor(part, 4);
                part += __shfl_xor(part, 8);
                if (c4 == 0) sc2[row] = part;   // exact fp32 ||c||^2
            }
        }
        __syncthreads();

        #pragma unroll
        for (int ct = 0; ct < 4; ++ct) {
            const int nrow = ct * 32 + l31;
            short8 bh[4], bl[4];
            #pragma unroll
            for (int ks = 0; ks < 4; ++ks) {
                bh[ks] = *(const short8*)&sB[nrow * 72 + ks * 16 + q * 8];
                bl[ks] = *(const short8*)&sB[9216 + nrow * 72 + ks * 16 + q * 8];
            }
            floatx16 a0, a1;
            #pragma unroll
            for (int r = 0; r < 16; ++r) { a0[r] = 0.f; a1[r] = 0.f; }
            #pragma unroll
            for (int ks = 0; ks < 4; ++ks) {   // hh, lh, hl passes; 2 indep chains
                a0 = __builtin_amdgcn_mfma_f32_32x32x16_bf16(ah[0][ks], bh[ks], a0, 0, 0, 0);
                a1 = __builtin_amdgcn_mfma_f32_32x32x16_bf16(ah[1][ks], bh[ks], a1, 0, 0, 0);
                a0 = __builtin_amdgcn_mfma_f32_32x32x16_bf16(al[0][ks], bh[ks], a0, 0, 0, 0);
                a1 = __builtin_amdgcn_mfma_f32_32x32x16_bf16(al[1][ks], bh[ks], a1, 0, 0, 0);
                a0 = __builtin_amdgcn_mfma_f32_32x32x16_bf16(ah[0][ks], bl[ks], a0, 0, 0, 0);
                a1 = __builtin_amdgcn_mfma_f32_32x32x16_bf16(ah[1][ks], bl[ks], a1, 0, 0, 0);
            }
            const float c2v  = sc2[nrow];
            const int   idxv = ch * 128 + nrow;
            #pragma unroll
            for (int r = 0; r < 16; ++r) {
                float s0 = fmaf(-2.f, a0[r], c2v);
                bool lt0 = s0 < bs[r];
                bs[r] = lt0 ? s0 : bs[r];
                bi[r] = lt0 ? idxv : bi[r];
                float s1 = fmaf(-2.f, a1[r], c2v);
                bool lt1 = s1 < bs[16 + r];
                bs[16 + r] = lt1 ? s1 : bs[16 + r];
                bi[16 + r] = lt1 ? idxv : bi[16 + r];
            }
        }
    }

    // ---- per-slot shfl butterfly: top-2 across the 32 column-classes ----
    #pragma unroll
    for (int s = 0; s < 32; ++s) {
        float b0 = bs[s]; int i0 = bi[s];
        float b1 = 3.4e38f; int i1 = 0x7fffffff;
        #pragma unroll
        for (int m = 1; m < 32; m <<= 1) {
            float ob0 = __shfl_xor(b0, m); int oi0 = __shfl_xor(i0, m);
            float ob1 = __shfl_xor(b1, m); int oi1 = __shfl_xor(i1, m);
            bool t = (ob0 < b0) || (ob0 == b0 && oi0 < i0);
            float hs = t ? b0 : ob0; int hi_ = t ? i0 : oi0;   // loser of firsts
            b0 = t ? ob0 : b0;       i0 = t ? oi0 : i0;
            bool u = (ob1 < b1) || (ob1 == b1 && oi1 < i1);
            float ms = u ? ob1 : b1; int mi = u ? oi1 : i1;    // winner of seconds
            bool z = (hs < ms) || (hs == ms && hi_ < mi);
            b1 = z ? hs : ms; i1 = z ? hi_ : mi;
        }
        if (l31 == s) {   // one writer per slot; all lanes hold identical result
            const int rt = s >> 4, r = s & 15;
            const int row = w * 64 + rt * 32 + (r & 3) + 8 * (r >> 2) + 4 * q;
            sci[row * 2]     = i0;
            sci[row * 2 + 1] = i1;
        }
    }
    __syncthreads();

    // ---- exact fp32 rescore (diff^2), 2 threads per point (split halves) ----
    #pragma unroll
    for (int it = 0; it < 2; ++it) {
        const int pid = it * 128 + (tid >> 1);
        const int h   = tid & 1;
        const int ia = sci[pid * 2], ib = sci[pid * 2 + 1];
        const float4* xr = x4 + (size_t)(base + pid) * 16 + h * 8;
        const float4* ca = c4p + (size_t)ia * 16 + h * 8;
        const float4* cb = c4p + (size_t)ib * 16 + h * 8;
        float da = 0.f, db = 0.f;
        #pragma unroll
        for (int j = 0; j < 8; ++j) {
            float4 xv = xr[j], av = ca[j], bv = cb[j];
            float4 d1 = make_float4(xv.x-av.x, xv.y-av.y, xv.z-av.z, xv.w-av.w);
            float4 d2 = make_float4(xv.x-bv.x, xv.y-bv.y, xv.z-bv.z, xv.w-bv.w);
            da += dot4(d1, d1);
            db += dot4(d2, d2);
        }
        da += __shfl_xor(da, 1);
        db += __shfl_xor(db, 1);
        if (h == 0) { sdd[pid * 2] = da; sdd[pid * 2 + 1] = db; }
    }
    __syncthreads();

    {   // final pick + scalar outputs (tie -> lower index, np argmin)
        const float da = sdd[tid * 2], db = sdd[tid * 2 + 1];
        const int   ia = sci[tid * 2], ib = sci[tid * 2 + 1];
        bool ta = (da < db) || (da == db && ia < ib);
        const int   bidx = ta ? ia : ib;
        const float bd   = ta ? da : db;
        out[base + tid]         = (float)bidx;
        out[N_PTS + base + tid] = sqrtf(fmaxf(bd, 0.f));
        sidx[tid] = bidx;
    }
    __syncthreads();

    // ---- gather quantized_data (coalesced float4 writes; cw is L2-hot) ----
    {
        float4* od = (float4*)(out + 2 * (size_t)N_PTS) + (size_t)base * 16;
        #pragma unroll
        for (int i = 0; i < 16; ++i) {
            const int g = i * 256 + tid;
            od[g] = c4p[(size_t)sidx[g >> 4] * 16 + (g & 15)];
        }
    }
}

extern "C" void kernel_launch(void* const* d_in, const int* in_sizes, int n_in,
                              void* d_out, int out_size, void* d_ws, size_t ws_size,
                              hipStream_t stream) {
    const float* x  = (const float*)d_in[0];
    const float* cw = (const float*)d_in[1];
    float* out = (float*)d_out;
    vq_kernel<<<N_PTS / 256, 256, 0, stream>>>(x, cw, out);
}

// Round 5
// 254.642 us; speedup vs baseline: 4.1795x; 1.1043x over previous
//
#include <hip/hip_runtime.h>

// VectorQuantizationLayer1D: N=262144 pts, D=64, K=1024 codewords.
// out (f32): [0,N) idx-as-float | [N,2N) dist | [2N,..) gathered codewords.
//
// Round 5: same proven split-bf16 3-pass MFMA selection + top-2 exact rescue.
// New: (a) prep kernel pre-splits codebook into hi/lo bf16 LDS-image chunks +
// exact ||c||^2 in d_ws (done once, not per block); (b) main kernel stages B
// via double-buffered global_load_lds width-16 (zero-VALU DMA), prefetch for
// ch+1 issued at top of compute(ch) so the pre-barrier vmcnt(0) drain is free.
// ws layout: 8 chunks x 36864 B (hi 128x72 shorts | lo 128x72 shorts), then
// c2[1024] floats at byte 294912. Needs ws_size >= 299008.

#define N_PTS 262144
#define K_CW  1024
#define DIM   64
#define CHUNK_B 36864           // bytes per chunk image (hi+lo, stride 72 shorts)
#define C2_OFF  (8 * CHUNK_B)   // byte offset of c2[] in ws

typedef __attribute__((ext_vector_type(8)))  short short8;
typedef __attribute__((ext_vector_type(16))) float floatx16;

__device__ __forceinline__ unsigned short f2bf(float f) {
    unsigned u = __float_as_uint(f);
    return (unsigned short)((u + 0x7FFFu + ((u >> 16) & 1u)) >> 16);
}
__device__ __forceinline__ float bf2f(unsigned short h) {
    return __uint_as_float(((unsigned)h) << 16);
}
__device__ __forceinline__ float dot4(float4 a, float4 b) {
    return a.x*b.x + a.y*b.y + a.z*b.z + a.w*b.w;
}
__device__ __forceinline__ void async_cp16(const void* g, void* l) {
    __builtin_amdgcn_global_load_lds(
        (const __attribute__((address_space(1))) unsigned int*)g,
        (__attribute__((address_space(3))) unsigned int*)l, 16, 0, 0);
}

// ---- prep: split codebook into bf16 hi/lo LDS-image + exact ||c||^2 ----
__global__ void vq_prep(const float* __restrict__ cw, unsigned char* __restrict__ ws) {
    const int k = blockIdx.x * 256 + threadIdx.x;   // codeword 0..1023
    const int ch = k >> 7, r = k & 127;
    unsigned short* chunk = (unsigned short*)(ws + (size_t)ch * CHUNK_B);
    unsigned short* hi = chunk + r * 72;
    unsigned short* lo = hi + 9216;
    const float4* cr = (const float4*)cw + (size_t)k * 16;
    float c2 = 0.f;
    #pragma unroll
    for (int j = 0; j < 16; ++j) {
        float4 v = cr[j];
        c2 += dot4(v, v);
        unsigned short h0 = f2bf(v.x), h1 = f2bf(v.y), h2 = f2bf(v.z), h3 = f2bf(v.w);
        unsigned short l0 = f2bf(v.x - bf2f(h0)), l1 = f2bf(v.y - bf2f(h1)),
                       l2 = f2bf(v.z - bf2f(h2)), l3 = f2bf(v.w - bf2f(h3));
        uint2 hv, lv;
        hv.x = (unsigned)h0 | ((unsigned)h1 << 16);
        hv.y = (unsigned)h2 | ((unsigned)h3 << 16);
        lv.x = (unsigned)l0 | ((unsigned)l1 << 16);
        lv.y = (unsigned)l2 | ((unsigned)l3 << 16);
        *(uint2*)(hi + j * 4) = hv;
        *(uint2*)(lo + j * 4) = lv;
    }
    ((float*)(ws + C2_OFF))[k] = c2;
}

__launch_bounds__(256, 2)
__global__ void vq_kernel(const float* __restrict__ x,
                          const float* __restrict__ cw,
                          const unsigned char* __restrict__ ws,
                          float* __restrict__ out) {
    __shared__ __align__(16) unsigned char sB[2 * CHUNK_B];   // 72 KB double buffer
    // epilogue scratch aliases buf0 (dead after the K loop)
    int*   sci  = (int*)sB;              // [0, 2048)
    float* sdd  = (float*)(sB + 2048);   // [2048, 4096)
    int*   sidx = (int*)(sB + 4096);     // [4096, 5120)

    const int tid  = threadIdx.x;
    const int w    = tid >> 6;
    const int lane = tid & 63;
    const int q    = lane >> 5;
    const int l31  = lane & 31;
    const int base = blockIdx.x * 256;
    const float4* __restrict__ x4  = (const float4*)x;
    const float4* __restrict__ c4p = (const float4*)cw;
    const float*  __restrict__ c2g = (const float*)(ws + C2_OFF);

    // ---- A fragments from global: wave w owns rows [w*64, w*64+64) ----
    short8 ah[2][4], al[2][4];
    #pragma unroll
    for (int rt = 0; rt < 2; ++rt) {
        const int row = w * 64 + rt * 32 + l31;
        const float4* xr = x4 + (size_t)(base + row) * 16;
        #pragma unroll
        for (int ks = 0; ks < 4; ++ks) {
            float4 va = xr[ks * 4 + q * 2];
            float4 vb = xr[ks * 4 + q * 2 + 1];
            float f[8] = {va.x, va.y, va.z, va.w, vb.x, vb.y, vb.z, vb.w};
            short8 h, l;
            #pragma unroll
            for (int j = 0; j < 8; ++j) {
                unsigned short hb = f2bf(f[j]);
                h[j] = (short)hb;
                l[j] = (short)f2bf(f[j] - bf2f(hb));
            }
            ah[rt][ks] = h; al[rt][ks] = l;
        }
    }

    float bs[32]; int bi[32];
    #pragma unroll
    for (int s = 0; s < 32; ++s) { bs[s] = 3.4e38f; bi[s] = 0; }

    // pre-issue chunk 0 DMA into buf0 (each wave copies its 9 KB quarter)
    {
        const unsigned char* g = ws + w * 9216 + lane * 16;
        unsigned char* l = sB + w * 9216;
        #pragma unroll
        for (int i = 0; i < 9; ++i) async_cp16(g + i * 1024, l + i * 1024);
    }

    // ---- K loop: 8 chunks of 128 codewords, single barrier per chunk ----
    for (int ch = 0; ch < 8; ++ch) {
        __syncthreads();   // own DMA drained (vmcnt0) + all waves' DMA for ch landed

        if (ch < 7) {      // prefetch ch+1 into other buffer; hidden under compute
            const unsigned char* g = ws + (size_t)(ch + 1) * CHUNK_B + w * 9216 + lane * 16;
            unsigned char* l = sB + ((ch + 1) & 1) * CHUNK_B + w * 9216;
            #pragma unroll
            for (int i = 0; i < 9; ++i) async_cp16(g + i * 1024, l + i * 1024);
        }

        float c2v[4];
        #pragma unroll
        for (int ct = 0; ct < 4; ++ct) c2v[ct] = c2g[ch * 128 + ct * 32 + l31];

        const unsigned short* bufS = (const unsigned short*)(sB + (ch & 1) * CHUNK_B);

        #pragma unroll
        for (int ct = 0; ct < 4; ++ct) {
            const int nrow = ct * 32 + l31;
            short8 bh[4], bl[4];
            #pragma unroll
            for (int ks = 0; ks < 4; ++ks) {
                bh[ks] = *(const short8*)&bufS[nrow * 72 + ks * 16 + q * 8];
                bl[ks] = *(const short8*)&bufS[9216 + nrow * 72 + ks * 16 + q * 8];
            }
            floatx16 a0, a1;
            #pragma unroll
            for (int r = 0; r < 16; ++r) { a0[r] = 0.f; a1[r] = 0.f; }
            #pragma unroll
            for (int ks = 0; ks < 4; ++ks) {   // hh, lh, hl; 2 indep chains
                a0 = __builtin_amdgcn_mfma_f32_32x32x16_bf16(ah[0][ks], bh[ks], a0, 0, 0, 0);
                a1 = __builtin_amdgcn_mfma_f32_32x32x16_bf16(ah[1][ks], bh[ks], a1, 0, 0, 0);
                a0 = __builtin_amdgcn_mfma_f32_32x32x16_bf16(al[0][ks], bh[ks], a0, 0, 0, 0);
                a1 = __builtin_amdgcn_mfma_f32_32x32x16_bf16(al[1][ks], bh[ks], a1, 0, 0, 0);
                a0 = __builtin_amdgcn_mfma_f32_32x32x16_bf16(ah[0][ks], bl[ks], a0, 0, 0, 0);
                a1 = __builtin_amdgcn_mfma_f32_32x32x16_bf16(ah[1][ks], bl[ks], a1, 0, 0, 0);
            }
            const int idxv = ch * 128 + nrow;
            #pragma unroll
            for (int r = 0; r < 16; ++r) {
                float s0 = fmaf(-2.f, a0[r], c2v[ct]);
                bool lt0 = s0 < bs[r];
                bs[r] = lt0 ? s0 : bs[r];
                bi[r] = lt0 ? idxv : bi[r];
                float s1 = fmaf(-2.f, a1[r], c2v[ct]);
                bool lt1 = s1 < bs[16 + r];
                bs[16 + r] = lt1 ? s1 : bs[16 + r];
                bi[16 + r] = lt1 ? idxv : bi[16 + r];
            }
        }
    }
    __syncthreads();   // all B reads done before buf0 is reused as scratch

    // ---- per-slot shfl butterfly: top-2 across the 32 column-classes ----
    #pragma unroll
    for (int s = 0; s < 32; ++s) {
        float b0 = bs[s]; int i0 = bi[s];
        float b1 = 3.4e38f; int i1 = 0x7fffffff;
        #pragma unroll
        for (int m = 1; m < 32; m <<= 1) {
            float ob0 = __shfl_xor(b0, m); int oi0 = __shfl_xor(i0, m);
            float ob1 = __shfl_xor(b1, m); int oi1 = __shfl_xor(i1, m);
            bool t = (ob0 < b0) || (ob0 == b0 && oi0 < i0);
            float hs = t ? b0 : ob0; int hi_ = t ? i0 : oi0;   // loser of firsts
            b0 = t ? ob0 : b0;       i0 = t ? oi0 : i0;
            bool u = (ob1 < b1) || (ob1 == b1 && oi1 < i1);
            float ms = u ? ob1 : b1; int mi = u ? oi1 : i1;    // winner of seconds
            bool z = (hs < ms) || (hs == ms && hi_ < mi);
            b1 = z ? hs : ms; i1 = z ? hi_ : mi;
        }
        if (l31 == s) {
            const int rt = s >> 4, r = s & 15;
            const int row = w * 64 + rt * 32 + (r & 3) + 8 * (r >> 2) + 4 * q;
            sci[row * 2]     = i0;
            sci[row * 2 + 1] = i1;
        }
    }
    __syncthreads();

    // ---- exact fp32 rescore (diff^2), 2 threads per point ----
    #pragma unroll
    for (int it = 0; it < 2; ++it) {
        const int pid = it * 128 + (tid >> 1);
        const int h   = tid & 1;
        const int ia = sci[pid * 2], ib = sci[pid * 2 + 1];
        const float4* xr = x4 + (size_t)(base + pid) * 16 + h * 8;
        const float4* ca = c4p + (size_t)ia * 16 + h * 8;
        const float4* cb = c4p + (size_t)ib * 16 + h * 8;
        float da = 0.f, db = 0.f;
        #pragma unroll
        for (int j = 0; j < 8; ++j) {
            float4 xv = xr[j], av = ca[j], bv = cb[j];
            float4 d1 = make_float4(xv.x-av.x, xv.y-av.y, xv.z-av.z, xv.w-av.w);
            float4 d2 = make_float4(xv.x-bv.x, xv.y-bv.y, xv.z-bv.z, xv.w-bv.w);
            da += dot4(d1, d1);
            db += dot4(d2, d2);
        }
        da += __shfl_xor(da, 1);
        db += __shfl_xor(db, 1);
        if (h == 0) { sdd[pid * 2] = da; sdd[pid * 2 + 1] = db; }
    }
    __syncthreads();

    {   // final pick + scalar outputs (tie -> lower index, np argmin)
        const float da = sdd[tid * 2], db = sdd[tid * 2 + 1];
        const int   ia = sci[tid * 2], ib = sci[tid * 2 + 1];
        bool ta = (da < db) || (da == db && ia < ib);
        const int   bidx = ta ? ia : ib;
        const float bd   = ta ? da : db;
        out[base + tid]         = (float)bidx;
        out[N_PTS + base + tid] = sqrtf(fmaxf(bd, 0.f));
        sidx[tid] = bidx;
    }
    __syncthreads();

    // ---- gather quantized_data (coalesced float4 writes; cw is L2-hot) ----
    {
        float4* od = (float4*)(out + 2 * (size_t)N_PTS) + (size_t)base * 16;
        #pragma unroll
        for (int i = 0; i < 16; ++i) {
            const int g = i * 256 + tid;
            od[g] = c4p[(size_t)sidx[g >> 4] * 16 + (g & 15)];
        }
    }
}

extern "C" void kernel_launch(void* const* d_in, const int* in_sizes, int n_in,
                              void* d_out, int out_size, void* d_ws, size_t ws_size,
                              hipStream_t stream) {
    const float* x  = (const float*)d_in[0];
    const float* cw = (const float*)d_in[1];
    float* out = (float*)d_out;
    unsigned char* ws = (unsigned char*)d_ws;
    vq_prep<<<4, 256, 0, stream>>>(cw, ws);
    vq_kernel<<<N_PTS / 256, 256, 0, stream>>>(x, cw, ws, out);
}